// Round 3
// baseline (52.363 us; speedup 1.0000x reference)
//
#include <hip/hip_runtime.h>
#include <math.h>

// DescGroupPoolandNorm (pool='shift', candidate='top1', norm='l2')
//   B=4, K=8192, CG=1024, G=8, C=128
//   s = argmax over g of desc[b,k, 0*G+g]  (first channel group, first-wins)
//   out[b,k, c*G+g] = desc[b,k, c*G + (g+s)%G] / (||desc[b,k,:]||_2 + 1e-6)
//   kpts passes through (fused as extra blocks).
// L2 norm is permutation-invariant -> single pass over the row.
// Output stores are non-temporal: write-once data, keep it out of L2/L3 so
// the 128 MB input stays resident in the 256 MB Infinity Cache across replays.

#define ROWLEN 1024  // CG

// clang-native vector type: __builtin_nontemporal_store requires it
// (HIP's float4 is a class and is rejected).
typedef float f32x4 __attribute__((ext_vector_type(4)));

__device__ __forceinline__ void nt_store4(float4 v, float4* p) {
    f32x4 w = {v.x, v.y, v.z, v.w};
    __builtin_nontemporal_store(w, (f32x4*)p);
}

template<int S>
__device__ __forceinline__ void roll_pair(const float4 a0, const float4 a1,
                                          const float inv,
                                          float4& o0, float4& o1) {
    const float f[8] = {a0.x, a0.y, a0.z, a0.w, a1.x, a1.y, a1.z, a1.w};
    o0.x = f[(S + 0) & 7] * inv;
    o0.y = f[(S + 1) & 7] * inv;
    o0.z = f[(S + 2) & 7] * inv;
    o0.w = f[(S + 3) & 7] * inv;
    o1.x = f[(S + 4) & 7] * inv;
    o1.y = f[(S + 5) & 7] * inv;
    o1.z = f[(S + 6) & 7] * inv;
    o1.w = f[(S + 7) & 7] * inv;
}

#define ROLL_CASE(S)                                                 \
    case S:                                                          \
        roll_pair<S>(a0, a1, inv, o0, o1);                           \
        roll_pair<S>(b0, b1, inv, o2, o3);                           \
        break;

__global__ __launch_bounds__(256) void REDFM_15676630630653_kernel(
    const float* __restrict__ desc, float* __restrict__ out,
    const float* __restrict__ kpts, float* __restrict__ kpts_out,
    int rows, int descBlocks) {
    if (blockIdx.x >= descBlocks) {
        // kpts pass-through: 64 blocks x 256 threads x 1 float4 = 256 KB
        const int i = (blockIdx.x - descBlocks) * 256 + threadIdx.x;
        const float4 v = ((const float4*)kpts)[i];
        nt_store4(v, ((float4*)kpts_out) + i);
        return;
    }

    const int gtid = blockIdx.x * 256 + threadIdx.x;
    const int r = gtid >> 6;          // one wave per row
    const int lane = threadIdx.x & 63;

    const float4* __restrict__ row = (const float4*)(desc + (size_t)r * ROWLEN);
    float4* __restrict__ orow = (float4*)(out + (size_t)r * ROWLEN);

    // Lane owns two full 8-float groups: group `lane` and group `lane+64`.
    const float4 a0 = row[2 * lane];
    const float4 a1 = row[2 * lane + 1];
    const float4 b0 = row[2 * lane + 128];
    const float4 b1 = row[2 * lane + 129];

    // Sum of squares of the 16 owned floats, then wave-wide reduce.
    float ss = a0.x * a0.x + a0.y * a0.y + a0.z * a0.z + a0.w * a0.w
             + a1.x * a1.x + a1.y * a1.y + a1.z * a1.z + a1.w * a1.w
             + b0.x * b0.x + b0.y * b0.y + b0.z * b0.z + b0.w * b0.w
             + b1.x * b1.x + b1.y * b1.y + b1.z * b1.z + b1.w * b1.w;
#pragma unroll
    for (int off = 1; off < 64; off <<= 1) ss += __shfl_xor(ss, off);
    const float inv = 1.0f / (sqrtf(ss) + 1e-6f);

    // argmax (first-wins) of row elements 0..7 — lane 0 owns them (a0,a1).
    const float vals[8] = {a0.x, a0.y, a0.z, a0.w, a1.x, a1.y, a1.z, a1.w};
    int bi = 0;
    float bv = vals[0];
#pragma unroll
    for (int m = 1; m < 8; m++) {
        if (vals[m] > bv) { bv = vals[m]; bi = m; }
    }
    // Broadcast lane 0's result; readfirstlane marks it wave-uniform (SGPR)
    // so the switch below is a scalar branch.
    const int s = __builtin_amdgcn_readfirstlane(bi);

    float4 o0, o1, o2, o3;
    switch (s) {
        ROLL_CASE(0)
        ROLL_CASE(1)
        ROLL_CASE(2)
        ROLL_CASE(3)
        ROLL_CASE(4)
        ROLL_CASE(5)
        ROLL_CASE(6)
        ROLL_CASE(7)
        default: o0 = o1 = o2 = o3 = make_float4(0.f, 0.f, 0.f, 0.f); break;
    }

    // Non-temporal: write-once stream, don't pollute L2/L3.
    nt_store4(o0, orow + 2 * lane);
    nt_store4(o1, orow + 2 * lane + 1);
    nt_store4(o2, orow + 2 * lane + 128);
    nt_store4(o3, orow + 2 * lane + 129);
}

extern "C" void kernel_launch(void* const* d_in, const int* in_sizes, int n_in,
                              void* d_out, int out_size, void* d_ws, size_t ws_size,
                              hipStream_t stream) {
    const float* kpts = (const float*)d_in[0];
    const float* desc = (const float*)d_in[1];
    float* out = (float*)d_out;

    const int kpts_elems = in_sizes[0];            // B*K*2 = 65536
    const int desc_elems = in_sizes[1];            // B*K*CG = 33554432
    const int rows = desc_elems / ROWLEN;          // B*K = 32768

    float* desc_out = out + kpts_elems;
    const int descBlocks = (rows * 64 + 255) / 256;          // 8192
    const int kptsBlocks = (kpts_elems / 4 + 255) / 256;     // 64
    REDFM_15676630630653_kernel<<<descBlocks + kptsBlocks, 256, 0, stream>>>(
        desc, desc_out, kpts, out, rows, descBlocks);
}

// Round 4
// 52.025 us; speedup vs baseline: 1.0065x; 1.0065x over previous
//
#include <hip/hip_runtime.h>
#include <math.h>

// DescGroupPoolandNorm (pool='shift', candidate='top1', norm='l2')
//   B=4, K=8192, CG=1024, G=8, C=128
//   s = argmax over g of desc[b,k, 0*G+g]  (first channel group, first-wins)
//   out[b,k, c*G+g] = desc[b,k, c*G + (g+s)%G] / (||desc[b,k,:]||_2 + 1e-6)
//   kpts passes through (fused as extra blocks).
// L2 norm is permutation-invariant -> single pass over the row.
//
// Round-4 structure: one wave owns RPW=4 consecutive rows (16 KB sequential
// stream) with 1-row software prefetch -> each wave always has a full row of
// loads in flight while computing/storing the current row. 2048 desc blocks
// x 4 waves = 8192 waves = 100% of chip wave capacity.

#define ROWLEN 1024  // CG (floats per row)
#define RPW 4        // rows per wave

template<int S>
__device__ __forceinline__ void roll_pair(const float4 a0, const float4 a1,
                                          const float inv,
                                          float4& o0, float4& o1) {
    const float f[8] = {a0.x, a0.y, a0.z, a0.w, a1.x, a1.y, a1.z, a1.w};
    o0.x = f[(S + 0) & 7] * inv;
    o0.y = f[(S + 1) & 7] * inv;
    o0.z = f[(S + 2) & 7] * inv;
    o0.w = f[(S + 3) & 7] * inv;
    o1.x = f[(S + 4) & 7] * inv;
    o1.y = f[(S + 5) & 7] * inv;
    o1.z = f[(S + 6) & 7] * inv;
    o1.w = f[(S + 7) & 7] * inv;
}

#define ROLL_CASE(S)                                                 \
    case S:                                                          \
        roll_pair<S>(a0, a1, inv, o0, o1);                           \
        roll_pair<S>(b0, b1, inv, o2, o3);                           \
        break;

// Process one row held in registers (a0,a1 = lane's group `lane`,
// b0,b1 = lane's group `lane+64`) and store the normalized rolled row.
__device__ __forceinline__ void process_row(const float4 a0, const float4 a1,
                                            const float4 b0, const float4 b1,
                                            float4* __restrict__ orow,
                                            const int lane) {
    // Sum of squares of the 16 owned floats, then wave-wide reduce.
    float ss = a0.x * a0.x + a0.y * a0.y + a0.z * a0.z + a0.w * a0.w
             + a1.x * a1.x + a1.y * a1.y + a1.z * a1.z + a1.w * a1.w
             + b0.x * b0.x + b0.y * b0.y + b0.z * b0.z + b0.w * b0.w
             + b1.x * b1.x + b1.y * b1.y + b1.z * b1.z + b1.w * b1.w;
#pragma unroll
    for (int off = 1; off < 64; off <<= 1) ss += __shfl_xor(ss, off);
    const float inv = 1.0f / (sqrtf(ss) + 1e-6f);

    // argmax (first-wins) of row elements 0..7 — lane 0 owns them (a0,a1).
    const float vals[8] = {a0.x, a0.y, a0.z, a0.w, a1.x, a1.y, a1.z, a1.w};
    int bi = 0;
    float bv = vals[0];
#pragma unroll
    for (int m = 1; m < 8; m++) {
        if (vals[m] > bv) { bv = vals[m]; bi = m; }
    }
    // Broadcast lane 0's result; readfirstlane marks it wave-uniform (SGPR)
    // so the switch below is a scalar branch.
    const int s = __builtin_amdgcn_readfirstlane(bi);

    float4 o0, o1, o2, o3;
    switch (s) {
        ROLL_CASE(0)
        ROLL_CASE(1)
        ROLL_CASE(2)
        ROLL_CASE(3)
        ROLL_CASE(4)
        ROLL_CASE(5)
        ROLL_CASE(6)
        ROLL_CASE(7)
        default: o0 = o1 = o2 = o3 = make_float4(0.f, 0.f, 0.f, 0.f); break;
    }

    orow[2 * lane] = o0;
    orow[2 * lane + 1] = o1;
    orow[2 * lane + 128] = o2;
    orow[2 * lane + 129] = o3;
}

__global__ __launch_bounds__(256) void REDFM_15676630630653_kernel(
    const float* __restrict__ desc, float* __restrict__ out,
    const float* __restrict__ kpts, float* __restrict__ kpts_out,
    int rows, int descBlocks) {
    if (blockIdx.x >= descBlocks) {
        // kpts pass-through: 64 blocks x 256 threads x 1 float4 = 256 KB
        const int i = (blockIdx.x - descBlocks) * 256 + threadIdx.x;
        ((float4*)kpts_out)[i] = ((const float4*)kpts)[i];
        return;
    }

    const int wid = (blockIdx.x * 256 + threadIdx.x) >> 6;  // global wave id
    const int lane = threadIdx.x & 63;
    const int r0 = wid * RPW;
    if (r0 >= rows) return;

    const float4* __restrict__ rowp = (const float4*)(desc + (size_t)r0 * ROWLEN);

    // Prologue: load row r0.
    float4 c0 = rowp[2 * lane];
    float4 c1 = rowp[2 * lane + 1];
    float4 c2 = rowp[2 * lane + 128];
    float4 c3 = rowp[2 * lane + 129];

#pragma unroll
    for (int i = 0; i < RPW; i++) {
        float4 n0, n1, n2, n3;
        if (i + 1 < RPW) {
            // Issue next row's loads BEFORE consuming current row -> the
            // vmcnt wait for c* leaves n* in flight under compute+stores.
            const float4* np = rowp + (size_t)(i + 1) * (ROWLEN / 4);
            n0 = np[2 * lane];
            n1 = np[2 * lane + 1];
            n2 = np[2 * lane + 128];
            n3 = np[2 * lane + 129];
        }
        process_row(c0, c1, c2, c3,
                    (float4*)(out + (size_t)(r0 + i) * ROWLEN), lane);
        if (i + 1 < RPW) { c0 = n0; c1 = n1; c2 = n2; c3 = n3; }
    }
}

extern "C" void kernel_launch(void* const* d_in, const int* in_sizes, int n_in,
                              void* d_out, int out_size, void* d_ws, size_t ws_size,
                              hipStream_t stream) {
    const float* kpts = (const float*)d_in[0];
    const float* desc = (const float*)d_in[1];
    float* out = (float*)d_out;

    const int kpts_elems = in_sizes[0];            // B*K*2 = 65536
    const int desc_elems = in_sizes[1];            // B*K*CG = 33554432
    const int rows = desc_elems / ROWLEN;          // B*K = 32768

    float* desc_out = out + kpts_elems;
    const int rowsPerBlock = 4 * RPW;                            // 16
    const int descBlocks = (rows + rowsPerBlock - 1) / rowsPerBlock;  // 2048
    const int kptsBlocks = (kpts_elems / 4 + 255) / 256;         // 64
    REDFM_15676630630653_kernel<<<descBlocks + kptsBlocks, 256, 0, stream>>>(
        desc, desc_out, kpts, out, rows, descBlocks);
}

// Round 5
// 48.427 us; speedup vs baseline: 1.0813x; 1.0743x over previous
//
#include <hip/hip_runtime.h>
#include <math.h>

// DescGroupPoolandNorm (pool='shift', candidate='top1', norm='l2')
//   B=4, K=8192, CG=1024, G=8, C=128
//   s = argmax over g of desc[b,k, g]  (first channel group, first-wins)
//   out[b,k, c*8+j] = desc[b,k, c*8 + (j+s)%8] / (||desc[b,k,:]||_2 + 1e-6)
//   kpts passes through (fused as extra blocks).
//
// Round-5: PACKED memory layout. Every load/store instruction is 64 lanes x
// 16 B contiguous (1024 B dense, 16 fully-consumed cache lines) instead of
// the previous stride-32B pattern (32 half-used lines per instr, 2x request
// rate). A group of 8 floats spans an even/odd lane pair; the roll becomes:
//   own  = lane's float4 (low half of group for even lanes, high for odd)
//   other= __shfl_xor(own,1)  (partner's half)
//   X = (s<4) ? own : other;  Y = (s<4) ? other : own;   // WAVE-UNIFORM
//   u = s & 3;  result = window [u..u+3] of concat(X,Y)   // uniform switch
// (the per-lane parity term cancels out of the X/Y select — verified:
//  window start w=(s+4p)&7, half h=(s>>2)^p, X=own iff p^h==0 iff s<4.)

#define ROWLEN 1024  // CG (floats per row)
#define RPW 4        // rows per wave

__device__ __forceinline__ float4 shfl_xor1(float4 v) {
    float4 r;
    r.x = __shfl_xor(v.x, 1);
    r.y = __shfl_xor(v.y, 1);
    r.z = __shfl_xor(v.z, 1);
    r.w = __shfl_xor(v.w, 1);
    return r;
}

// Window [U..U+3] of concat(X[0..3], Y[0..3]), scaled by inv.
template<int U>
__device__ __forceinline__ float4 window4(float4 X, float4 Y, float inv);
template<> __device__ __forceinline__ float4 window4<0>(float4 X, float4 Y, float inv) {
    return make_float4(X.x * inv, X.y * inv, X.z * inv, X.w * inv);
}
template<> __device__ __forceinline__ float4 window4<1>(float4 X, float4 Y, float inv) {
    return make_float4(X.y * inv, X.z * inv, X.w * inv, Y.x * inv);
}
template<> __device__ __forceinline__ float4 window4<2>(float4 X, float4 Y, float inv) {
    return make_float4(X.z * inv, X.w * inv, Y.x * inv, Y.y * inv);
}
template<> __device__ __forceinline__ float4 window4<3>(float4 X, float4 Y, float inv) {
    return make_float4(X.w * inv, Y.x * inv, Y.y * inv, Y.z * inv);
}

__device__ __forceinline__ void process_row_packed(
    const float4 v0, const float4 v1, const float4 v2, const float4 v3,
    float4* __restrict__ orow4, const int lane) {
    // ---- L2 norm (permutation-invariant): sum of squares + butterfly ----
    float ss = v0.x * v0.x + v0.y * v0.y + v0.z * v0.z + v0.w * v0.w
             + v1.x * v1.x + v1.y * v1.y + v1.z * v1.z + v1.w * v1.w
             + v2.x * v2.x + v2.y * v2.y + v2.z * v2.z + v2.w * v2.w
             + v3.x * v3.x + v3.y * v3.y + v3.z * v3.z + v3.w * v3.w;
#pragma unroll
    for (int off = 1; off < 64; off <<= 1) ss += __shfl_xor(ss, off);
    const float inv = 1.0f / (sqrtf(ss) + 1e-6f);

    // ---- argmax of row floats 0..7 (lane0: f0..3, lane1: f4..7) ----
    int bi_l = 0;
    float bv_l = v0.x;
    if (v0.y > bv_l) { bv_l = v0.y; bi_l = 1; }
    if (v0.z > bv_l) { bv_l = v0.z; bi_l = 2; }
    if (v0.w > bv_l) { bv_l = v0.w; bi_l = 3; }
    const float bv0 = __shfl(bv_l, 0);
    const float bv1 = __shfl(bv_l, 1);
    const int bi0 = __shfl(bi_l, 0);
    const int bi1 = __shfl(bi_l, 1);
    int s = (bv1 > bv0) ? (bi1 + 4) : bi0;  // first-wins: tie keeps lane0
    s = __builtin_amdgcn_readfirstlane(s);  // wave-uniform -> scalar branches

    // ---- partner halves ----
    const float4 o0 = shfl_xor1(v0);
    const float4 o1 = shfl_xor1(v1);
    const float4 o2 = shfl_xor1(v2);
    const float4 o3 = shfl_xor1(v3);

    // Wave-uniform X/Y select (parity cancels; see header comment).
    float4 X0, X1, X2, X3, Y0, Y1, Y2, Y3;
    if (s < 4) {
        X0 = v0; X1 = v1; X2 = v2; X3 = v3;
        Y0 = o0; Y1 = o1; Y2 = o2; Y3 = o3;
    } else {
        X0 = o0; X1 = o1; X2 = o2; X3 = o3;
        Y0 = v0; Y1 = v1; Y2 = v2; Y3 = v3;
    }

    float4 r0, r1, r2, r3;
    switch (s & 3) {  // uniform residual shift, compile-time indices
        case 0:
            r0 = window4<0>(X0, Y0, inv); r1 = window4<0>(X1, Y1, inv);
            r2 = window4<0>(X2, Y2, inv); r3 = window4<0>(X3, Y3, inv);
            break;
        case 1:
            r0 = window4<1>(X0, Y0, inv); r1 = window4<1>(X1, Y1, inv);
            r2 = window4<1>(X2, Y2, inv); r3 = window4<1>(X3, Y3, inv);
            break;
        case 2:
            r0 = window4<2>(X0, Y0, inv); r1 = window4<2>(X1, Y1, inv);
            r2 = window4<2>(X2, Y2, inv); r3 = window4<2>(X3, Y3, inv);
            break;
        default:
            r0 = window4<3>(X0, Y0, inv); r1 = window4<3>(X1, Y1, inv);
            r2 = window4<3>(X2, Y2, inv); r3 = window4<3>(X3, Y3, inv);
            break;
    }

    // Packed stores: 1024 B dense per instruction.
    orow4[lane] = r0;
    orow4[lane + 64] = r1;
    orow4[lane + 128] = r2;
    orow4[lane + 192] = r3;
}

__global__ __launch_bounds__(256) void REDFM_15676630630653_kernel(
    const float* __restrict__ desc, float* __restrict__ out,
    const float* __restrict__ kpts, float* __restrict__ kpts_out,
    int rows, int descBlocks) {
    if (blockIdx.x >= descBlocks) {
        // kpts pass-through: 64 blocks x 256 threads x 1 float4 = 256 KB
        const int i = (blockIdx.x - descBlocks) * 256 + threadIdx.x;
        ((float4*)kpts_out)[i] = ((const float4*)kpts)[i];
        return;
    }

    const int wid = (blockIdx.x * 256 + threadIdx.x) >> 6;  // global wave id
    const int lane = threadIdx.x & 63;
    const int r0 = wid * RPW;
    if (r0 >= rows) return;

    const float4* __restrict__ rowp = (const float4*)(desc + (size_t)r0 * ROWLEN);

    // Prologue: load row r0 (packed: each instr = 1024 B contiguous).
    float4 c0 = rowp[lane];
    float4 c1 = rowp[lane + 64];
    float4 c2 = rowp[lane + 128];
    float4 c3 = rowp[lane + 192];

#pragma unroll
    for (int i = 0; i < RPW; i++) {
        float4 n0, n1, n2, n3;
        if (i + 1 < RPW) {
            const float4* np = rowp + (size_t)(i + 1) * (ROWLEN / 4);
            n0 = np[lane];
            n1 = np[lane + 64];
            n2 = np[lane + 128];
            n3 = np[lane + 192];
        }
        process_row_packed(c0, c1, c2, c3,
                           (float4*)(out + (size_t)(r0 + i) * ROWLEN), lane);
        if (i + 1 < RPW) { c0 = n0; c1 = n1; c2 = n2; c3 = n3; }
    }
}

extern "C" void kernel_launch(void* const* d_in, const int* in_sizes, int n_in,
                              void* d_out, int out_size, void* d_ws, size_t ws_size,
                              hipStream_t stream) {
    const float* kpts = (const float*)d_in[0];
    const float* desc = (const float*)d_in[1];
    float* out = (float*)d_out;

    const int kpts_elems = in_sizes[0];            // B*K*2 = 65536
    const int desc_elems = in_sizes[1];            // B*K*CG = 33554432
    const int rows = desc_elems / ROWLEN;          // B*K = 32768

    float* desc_out = out + kpts_elems;
    const int rowsPerBlock = 4 * RPW;                                 // 16
    const int descBlocks = (rows + rowsPerBlock - 1) / rowsPerBlock;  // 2048
    const int kptsBlocks = (kpts_elems / 4 + 255) / 256;              // 64
    REDFM_15676630630653_kernel<<<descBlocks + kptsBlocks, 256, 0, stream>>>(
        desc, desc_out, kpts, out, rows, descBlocks);
}